// Round 5
// baseline (423.711 us; speedup 1.0000x reference)
//
#include <hip/hip_runtime.h>

// Depthwise 7x7 VALID conv, fp32, NCHW.
// x: (16,256,128,128), w: (256,7,7), out: (16,256,122,122)
// No LDS. Each thread: 4x8 output micro-tile, 10 rows x 4 float4 loads
// (all 16B-aligned), prefetch-distance-1 rotation, weights in SGPRs via
// readfirstlane. tx=15 computes 8 cols but stores only 2 (masked); its
// upper load chunks clamp to col 124 (in-bounds garbage, masked out).

#define BATCH 16
#define CHAN  256
#define H_IN  128
#define W_IN  128
#define KS    7
#define H_OUT 122
#define W_OUT 122

#define RB 4           // output rows per thread
#define CB 8           // output cols per thread

typedef float v2f __attribute__((ext_vector_type(2)));

__device__ __forceinline__ float sgpr_bcast(float v) {
    return __int_as_float(__builtin_amdgcn_readfirstlane(__float_as_int(v)));
}

__global__ __launch_bounds__(256)
void dwconv7x7_kernel(const float* __restrict__ x,
                      const float* __restrict__ w,
                      float* __restrict__ out) {
    const int img = blockIdx.y;                 // b*CHAN + c
    const int ch  = img & (CHAN - 1);

    const int tx = threadIdx.x & 15;            // 16 col groups x 8 = 128 cols
    const int ty = threadIdx.x >> 4;            // 16 row groups x 4 = 64 rows

    const int ox = tx * CB;                     // 0..120 (tx=15 partially masked)
    const int y0 = (blockIdx.x == 0) ? 0 : (H_OUT - 64);   // 0 or 58
    const int oy = y0 + ty * RB;                // <=118; input rows oy..oy+9 <=127

    // ---- weights: block-uniform -> force into SGPRs ----
    const float* __restrict__ wp = w + ch * (KS * KS);
    float wr[KS * KS];
    #pragma unroll
    for (int i = 0; i < KS * KS; ++i) wr[i] = sgpr_bcast(wp[i]);

    // ---- load column bases: all multiples of 4 (16B-aligned), in-bounds ----
    const int c0 = ox;
    const int c1 = ox + 4;                          // <=124
    const int c2 = (ox + 8  <= 124) ? ox + 8  : 124;  // clamp only tx=15
    const int c3 = (ox + 12 <= 124) ? ox + 12 : 124;  // clamp tx>=14 dup ok

    const float* __restrict__ xp =
        x + (size_t)img * (H_IN * W_IN) + (size_t)oy * W_IN;

    float acc[RB][CB] = {};

    float4 n0 = *reinterpret_cast<const float4*>(xp + c0);
    float4 n1 = *reinterpret_cast<const float4*>(xp + c1);
    float4 n2 = *reinterpret_cast<const float4*>(xp + c2);
    float4 n3 = *reinterpret_cast<const float4*>(xp + c3);

    #pragma unroll
    for (int r = 0; r < RB + KS - 1; ++r) {     // 10 input rows
        const float4 a0 = n0, a1 = n1, a2 = n2, a3 = n3;
        if (r < RB + KS - 2) {                  // prefetch next row
            const float* row = xp + (r + 1) * W_IN;
            n0 = *reinterpret_cast<const float4*>(row + c0);
            n1 = *reinterpret_cast<const float4*>(row + c1);
            n2 = *reinterpret_cast<const float4*>(row + c2);
            n3 = *reinterpret_cast<const float4*>(row + c3);
        }
        float win[16];
        win[0]=a0.x;  win[1]=a0.y;  win[2]=a0.z;  win[3]=a0.w;
        win[4]=a1.x;  win[5]=a1.y;  win[6]=a1.z;  win[7]=a1.w;
        win[8]=a2.x;  win[9]=a2.y;  win[10]=a2.z; win[11]=a2.w;
        win[12]=a3.x; win[13]=a3.y; win[14]=a3.z; win[15]=a3.w;

        #pragma unroll
        for (int i = 0; i < RB; ++i) {
            const int ky = r - i;
            if (ky >= 0 && ky < KS) {
                #pragma unroll
                for (int kx = 0; kx < KS; ++kx) {
                    const float wv = wr[ky * KS + kx];
                    #pragma unroll
                    for (int cc = 0; cc < CB; ++cc)
                        acc[i][cc] = fmaf(win[kx + cc], wv, acc[i][cc]);
                }
            }
        }
    }

    // ---- stores: float2, mask cols >= W_OUT (only tx=15 lanes) ----
    float* __restrict__ op =
        out + (size_t)img * (H_OUT * W_OUT) + (size_t)oy * W_OUT + ox;
    #pragma unroll
    for (int i = 0; i < RB; ++i) {
        float* q = op + i * W_OUT;
        #pragma unroll
        for (int j = 0; j < CB / 2; ++j) {
            if (ox + 2 * j <= W_OUT - 2) {
                v2f v;
                v.x = acc[i][2 * j];
                v.y = acc[i][2 * j + 1];
                __builtin_nontemporal_store(v, reinterpret_cast<v2f*>(q) + j);
            }
        }
    }
}

extern "C" void kernel_launch(void* const* d_in, const int* in_sizes, int n_in,
                              void* d_out, int out_size, void* d_ws, size_t ws_size,
                              hipStream_t stream) {
    const float* x = (const float*)d_in[0];
    const float* w = (const float*)d_in[1];
    float* out = (float*)d_out;

    dim3 grid(2, BATCH * CHAN, 1);   // 2 row-tiles x 4096 images
    dim3 block(256, 1, 1);
    dwconv7x7_kernel<<<grid, block, 0, stream>>>(x, w, out);
}